// Round 1
// baseline (375.968 us; speedup 1.0000x reference)
//
#include <hip/hip_runtime.h>
#include <cstdint>

// ---------------------------------------------------------------------------
// AriaTextMoELayer: router(top2+softmax) -> grouped expert SwiGLU MLP ->
// combine, plus shared-expert SwiGLU MLP. N=2048 tokens, H=I=1024, ISH=2048.
// Strategy: bf16 MFMA (16x16x32) grouped GEMMs; fp32 accumulate; fp32 out.
// ws layout (~36.2 MB): scores | cnt | offs | list | x_bf | act | tmp | outbuf
// ---------------------------------------------------------------------------

#define E_ 8
#define H_ 1024
#define I_ 1024
#define ISH_ 2048
#define NTOK 2048

#define BM 128
#define BN 64
#define BK 32
#define PK (BK + 8)   // padded LDS row (u16 units): 80B stride -> 2-way banks (free)

typedef unsigned short u16;
using bf16x8 = __attribute__((ext_vector_type(8))) __bf16;
using f32x4  = __attribute__((ext_vector_type(4))) float;

__device__ __forceinline__ u16 f2bf(float f) {
  union { float f; unsigned u; } v; v.f = f;
  unsigned r = v.u + 0x7fffu + ((v.u >> 16) & 1u);  // RNE
  return (u16)(r >> 16);
}

// ---------------- router: one wave per token ----------------
__global__ void router_k(const float* __restrict__ x, const float* __restrict__ wr,
                         float* __restrict__ scores, int* __restrict__ cnt,
                         int* __restrict__ list) {
  int wid = threadIdx.x >> 6, lane = threadIdx.x & 63;
  int tk = blockIdx.x * 4 + wid;
  if (tk >= NTOK) return;
  const float* xr = x + (size_t)tk * H_;
  float acc[E_];
#pragma unroll
  for (int e = 0; e < E_; ++e) acc[e] = 0.f;
  int h0 = lane * 16;
#pragma unroll 4
  for (int i = 0; i < 16; ++i) {
    float xv = xr[h0 + i];
    const float* w = wr + (size_t)(h0 + i) * E_;
#pragma unroll
    for (int e = 0; e < E_; ++e) acc[e] = fmaf(xv, w[e], acc[e]);
  }
#pragma unroll
  for (int off = 32; off > 0; off >>= 1) {
#pragma unroll
    for (int e = 0; e < E_; ++e) acc[e] += __shfl_xor(acc[e], off, 64);
  }
  if (lane == 0) {
    int e0 = 0; float m0 = acc[0];
#pragma unroll
    for (int e = 1; e < E_; ++e) if (acc[e] > m0) { m0 = acc[e]; e0 = e; }
    int e1 = -1; float m1 = -1e30f;
#pragma unroll
    for (int e = 0; e < E_; ++e) if (e != e0 && acc[e] > m1) { m1 = acc[e]; e1 = e; }
    float s0 = 1.f / (1.f + __expf(m1 - m0));  // softmax over {m0, m1}, m0 >= m1
    scores[tk * 2 + 0] = s0;
    scores[tk * 2 + 1] = 1.f - s0;
    int p0 = atomicAdd(&cnt[e0], 1); list[e0 * NTOK + p0] = tk * 2;
    int p1 = atomicAdd(&cnt[e1], 1); list[e1 * NTOK + p1] = tk * 2 + 1;
  }
}

__global__ void offs_k(const int* __restrict__ cnt, int* __restrict__ offs) {
  if (threadIdx.x == 0 && blockIdx.x == 0) {
    int s = 0;
    for (int e = 0; e < E_; ++e) { offs[e] = s; s += cnt[e]; }
  }
}

__global__ void cvt_k(const float* __restrict__ x, u16* __restrict__ xb, int n4) {
  int i = blockIdx.x * blockDim.x + threadIdx.x;
  if (i >= n4) return;
  float4 v = reinterpret_cast<const float4*>(x)[i];
  ushort4 o;
  o.x = f2bf(v.x); o.y = f2bf(v.y); o.z = f2bf(v.z); o.w = f2bf(v.w);
  reinterpret_cast<ushort4*>(xb)[i] = o;
}

// ---------------- fused SwiGLU GEMM: Out = bf16( silu(A@B1) * (A@B2) ) -------
// EXPERT=1: grouped by blockIdx.z=e, A rows gathered via list (token = slot>>1),
//           out rows compacted at offs[e]. EXPERT=0: dense (shared experts).
template <int EXPERT>
__global__ __launch_bounds__(256) void swiglu_gemm_k(
    const u16* __restrict__ A, int lda,
    const int* __restrict__ list, const int* __restrict__ cnt, const int* __restrict__ offs,
    const float* __restrict__ B1g, const float* __restrict__ B2g, int ldb, long long bstride,
    u16* __restrict__ Out, int ldo, int K) {
  __shared__ u16 As[BM][PK];
  __shared__ u16 Bs[2][BN][PK];

  int e  = EXPERT ? blockIdx.z : 0;
  int Me = EXPERT ? cnt[e] : NTOK;
  int m0 = blockIdx.y * BM;
  if (m0 >= Me) return;
  int n0 = blockIdx.x * BN;
  const int* rowmap = EXPERT ? (list + e * NTOK) : nullptr;
  const float* B1 = B1g + (EXPERT ? (long long)e * bstride : 0);
  const float* B2 = B2g + (EXPERT ? (long long)e * bstride : 0);

  int t = threadIdx.x;
  int wid = t >> 6, lane = t & 63;
  int wm = wid & 1, wn = wid >> 1;
  int lr = lane & 15, lkg = lane >> 4;

  f32x4 accP[4][2] = {};
  f32x4 accG[4][2] = {};

  for (int k0 = 0; k0 < K; k0 += BK) {
    // stage A tile [BM][BK] (bf16 source), gathered rows, zero-fill tail
#pragma unroll
    for (int it = 0; it < 2; ++it) {
      int idx = it * 256 + t;
      int r = idx >> 2, q = idx & 3;
      int row = m0 + r;
      uint4 v = make_uint4(0u, 0u, 0u, 0u);
      if (row < Me) {
        int rg = EXPERT ? (rowmap[row] >> 1) : row;
        v = *reinterpret_cast<const uint4*>(A + (size_t)rg * lda + k0 + q * 8);
      }
      *reinterpret_cast<uint4*>(&As[r][q * 8]) = v;
    }
    // stage B tiles [BK][BN] fp32 -> bf16, transposed into [BN][BK]
#pragma unroll
    for (int b = 0; b < 2; ++b) {
      const float* Bp = b ? B2 : B1;
#pragma unroll
      for (int it = 0; it < 2; ++it) {
        int idx = (it * 256 + t) * 4;
        int kr = idx >> 6, c = idx & 63;
        float4 f = *reinterpret_cast<const float4*>(Bp + (size_t)(k0 + kr) * ldb + n0 + c);
        Bs[b][c + 0][kr] = f2bf(f.x);
        Bs[b][c + 1][kr] = f2bf(f.y);
        Bs[b][c + 2][kr] = f2bf(f.z);
        Bs[b][c + 3][kr] = f2bf(f.w);
      }
    }
    __syncthreads();
    bf16x8 af[4];
#pragma unroll
    for (int fm = 0; fm < 4; ++fm)
      af[fm] = *reinterpret_cast<const bf16x8*>(&As[wm * 64 + fm * 16 + lr][lkg * 8]);
#pragma unroll
    for (int fn = 0; fn < 2; ++fn) {
      bf16x8 bp = *reinterpret_cast<const bf16x8*>(&Bs[0][wn * 32 + fn * 16 + lr][lkg * 8]);
      bf16x8 bg = *reinterpret_cast<const bf16x8*>(&Bs[1][wn * 32 + fn * 16 + lr][lkg * 8]);
#pragma unroll
      for (int fm = 0; fm < 4; ++fm) {
        accP[fm][fn] = __builtin_amdgcn_mfma_f32_16x16x32_bf16(af[fm], bp, accP[fm][fn], 0, 0, 0);
        accG[fm][fn] = __builtin_amdgcn_mfma_f32_16x16x32_bf16(af[fm], bg, accG[fm][fn], 0, 0, 0);
      }
    }
    __syncthreads();
  }
  // epilogue: silu(p)*g -> bf16
#pragma unroll
  for (int fm = 0; fm < 4; ++fm) {
#pragma unroll
    for (int fn = 0; fn < 2; ++fn) {
#pragma unroll
      for (int j = 0; j < 4; ++j) {
        int grow = wm * 64 + fm * 16 + lkg * 4 + j;
        int gcol = wn * 32 + fn * 16 + lr;
        int row = m0 + grow;
        if (row < Me) {
          float p = accP[fm][fn][j], g = accG[fm][fn][j];
          float s = p / (1.f + __expf(-p)) * g;
          int orow = EXPERT ? (offs[e] + row) : row;
          Out[(size_t)orow * ldo + n0 + gcol] = f2bf(s);
        }
      }
    }
  }
}

// ---------------- plain GEMM (A bf16 @ B fp32->bf16) with two epilogues -----
// EXPERT=1 (fc2): scale row by scores[slot], scatter to outbuf[slot].
// EXPERT=0 (down): add outbuf[2t]+outbuf[2t+1], write final fp32 out.
template <int EXPERT>
__global__ __launch_bounds__(256) void out_gemm_k(
    const u16* __restrict__ A, int lda,
    const int* __restrict__ cnt, const int* __restrict__ offs,
    const int* __restrict__ list, const float* __restrict__ scores,
    const float* __restrict__ Bg, int ldb, long long bstride,
    float* __restrict__ Out, const float* __restrict__ outbuf, int K) {
  __shared__ u16 As[BM][PK];
  __shared__ u16 Bs[BN][PK];

  int e  = EXPERT ? blockIdx.z : 0;
  int Me = EXPERT ? cnt[e] : NTOK;
  int m0 = blockIdx.y * BM;
  if (m0 >= Me) return;
  int n0 = blockIdx.x * BN;
  const float* B = Bg + (EXPERT ? (long long)e * bstride : 0);
  int aoff = EXPERT ? offs[e] : 0;

  int t = threadIdx.x;
  int wid = t >> 6, lane = t & 63;
  int wm = wid & 1, wn = wid >> 1;
  int lr = lane & 15, lkg = lane >> 4;

  f32x4 acc[4][2] = {};

  for (int k0 = 0; k0 < K; k0 += BK) {
#pragma unroll
    for (int it = 0; it < 2; ++it) {
      int idx = it * 256 + t;
      int r = idx >> 2, q = idx & 3;
      int row = m0 + r;
      uint4 v = make_uint4(0u, 0u, 0u, 0u);
      if (row < Me)
        v = *reinterpret_cast<const uint4*>(A + (size_t)(aoff + row) * lda + k0 + q * 8);
      *reinterpret_cast<uint4*>(&As[r][q * 8]) = v;
    }
#pragma unroll
    for (int it = 0; it < 2; ++it) {
      int idx = (it * 256 + t) * 4;
      int kr = idx >> 6, c = idx & 63;
      float4 f = *reinterpret_cast<const float4*>(B + (size_t)(k0 + kr) * ldb + n0 + c);
      Bs[c + 0][kr] = f2bf(f.x);
      Bs[c + 1][kr] = f2bf(f.y);
      Bs[c + 2][kr] = f2bf(f.z);
      Bs[c + 3][kr] = f2bf(f.w);
    }
    __syncthreads();
    bf16x8 af[4];
#pragma unroll
    for (int fm = 0; fm < 4; ++fm)
      af[fm] = *reinterpret_cast<const bf16x8*>(&As[wm * 64 + fm * 16 + lr][lkg * 8]);
#pragma unroll
    for (int fn = 0; fn < 2; ++fn) {
      bf16x8 bb = *reinterpret_cast<const bf16x8*>(&Bs[wn * 32 + fn * 16 + lr][lkg * 8]);
#pragma unroll
      for (int fm = 0; fm < 4; ++fm)
        acc[fm][fn] = __builtin_amdgcn_mfma_f32_16x16x32_bf16(af[fm], bb, acc[fm][fn], 0, 0, 0);
    }
    __syncthreads();
  }
#pragma unroll
  for (int fm = 0; fm < 4; ++fm) {
#pragma unroll
    for (int fn = 0; fn < 2; ++fn) {
#pragma unroll
      for (int j = 0; j < 4; ++j) {
        int grow = wm * 64 + fm * 16 + lkg * 4 + j;
        int gcol = wn * 32 + fn * 16 + lr;
        int row = m0 + grow;
        if (row < Me) {
          float v = acc[fm][fn][j];
          int c = n0 + gcol;
          if (EXPERT) {
            int slot = list[e * NTOK + row];
            Out[(size_t)slot * H_ + c] = v * scores[slot];
          } else {
            Out[(size_t)row * H_ + c] =
                v + outbuf[(size_t)(2 * row) * H_ + c] + outbuf[(size_t)(2 * row + 1) * H_ + c];
          }
        }
      }
    }
  }
}

// ---------------------------------------------------------------------------
extern "C" void kernel_launch(void* const* d_in, const int* in_sizes, int n_in,
                              void* d_out, int out_size, void* d_ws, size_t ws_size,
                              hipStream_t stream) {
  const float* x   = (const float*)d_in[0];  // [2,1024,1024]
  const float* wr  = (const float*)d_in[1];  // [1024,8]
  const float* fc1 = (const float*)d_in[2];  // [8,1024,2048]
  const float* fc2 = (const float*)d_in[3];  // [8,1024,1024]
  const float* gw  = (const float*)d_in[4];  // [1024,2048]
  const float* uw  = (const float*)d_in[5];  // [1024,2048]
  const float* dw  = (const float*)d_in[6];  // [2048,1024]
  float* out = (float*)d_out;

  char* ws = (char*)d_ws;
  float* scores = (float*)(ws);                              // 16 KB
  int*   cnt    = (int*)(ws + (16 << 10));                   // 32 B
  int*   offs   = (int*)(ws + (16 << 10) + 128);
  int*   list   = (int*)(ws + (16 << 10) + 256);             // 64 KB
  u16*   xb     = (u16*)(ws + (96 << 10));                   // 4 MB
  u16*   act    = (u16*)(ws + (96 << 10) + (4ll << 20));     // 8 MB
  u16*   tmp    = (u16*)(ws + (96 << 10) + (12ll << 20));    // 8 MB
  float* outbuf = (float*)(ws + (96 << 10) + (20ll << 20));  // 16 MB -> total ~36.2 MB

  hipMemsetAsync(cnt, 0, E_ * sizeof(int), stream);
  router_k<<<NTOK / 4, 256, 0, stream>>>(x, wr, scores, cnt, list);
  offs_k<<<1, 64, 0, stream>>>(cnt, offs);
  cvt_k<<<(NTOK * H_ / 4 + 255) / 256, 256, 0, stream>>>(x, xb, NTOK * H_ / 4);

  // G1: expert fc1 + SwiGLU -> act (bf16, rows compacted by expert)
  swiglu_gemm_k<1><<<dim3(I_ / BN, NTOK / BM, E_), 256, 0, stream>>>(
      xb, H_, list, cnt, offs, fc1, fc1 + I_, 2 * I_, (long long)H_ * 2 * I_, act, I_, H_);
  // G2: expert fc2, scale by score, scatter -> outbuf[slot]
  out_gemm_k<1><<<dim3(H_ / BN, NTOK / BM, E_), 256, 0, stream>>>(
      act, I_, cnt, offs, list, scores, fc2, H_, (long long)I_ * H_, outbuf, nullptr, I_);
  // G3: shared gate/up + SwiGLU -> tmp (bf16)
  swiglu_gemm_k<0><<<dim3(ISH_ / BN, NTOK / BM, 1), 256, 0, stream>>>(
      xb, H_, nullptr, nullptr, nullptr, gw, uw, ISH_, 0, tmp, ISH_, H_);
  // G4: shared down + combine moe slots -> final fp32 out
  out_gemm_k<0><<<dim3(H_ / BN, NTOK / BM, 1), 256, 0, stream>>>(
      tmp, ISH_, nullptr, nullptr, nullptr, nullptr, dw, H_, 0, out, outbuf, ISH_);

  (void)in_sizes; (void)n_in; (void)out_size; (void)ws_size;
}

// Round 2
// 252.643 us; speedup vs baseline: 1.4881x; 1.4881x over previous
//
#include <hip/hip_runtime.h>
#include <cstdint>

// ---------------------------------------------------------------------------
// AriaTextMoELayer R2: m97-style bf16 MFMA GEMMs with global_load_lds staging.
// prep_k: router + x->bf16 + all-weight fp32->bf16 transpose ([K][N]->[N][K]).
// L1: fused G1 (expert fc1+SwiGLU, gathered rows) + G3 (shared gate/up+SwiGLU).
// L2: G2 (expert fc2, score-scale, scatter->outbuf bf16).
// L3: G4 (shared down + combine outbuf slots -> fp32 out).
// Fast path needs ~92.4 MB ws; falls back to the proven R1 path otherwise.
// ---------------------------------------------------------------------------

#define E_ 8
#define H_ 1024
#define I_ 1024
#define ISH_ 2048
#define NTOK 2048

typedef unsigned short u16;
using bf16x8 = __attribute__((ext_vector_type(8))) __bf16;
using f32x4  = __attribute__((ext_vector_type(4))) float;

__device__ __forceinline__ u16 f2bf(float f) {
  union { float f; unsigned u; } v; v.f = f;
  unsigned r = v.u + 0x7fffu + ((v.u >> 16) & 1u);  // RNE
  return (u16)(r >> 16);
}
__device__ __forceinline__ float bf2f(u16 u) {
  union { unsigned u; float f; } v; v.u = ((unsigned)u) << 16; return v.f;
}

typedef __attribute__((address_space(1))) const void glb_v;
typedef __attribute__((address_space(3))) void lds_v;
__device__ __forceinline__ void gl16(const void* g, void* l) {
  // async global->LDS, 16B/lane; LDS dest = wave-uniform base + lane*16
  __builtin_amdgcn_global_load_lds((glb_v*)g, (lds_v*)l, 16, 0, 0);
}

// ---------------- router core: one wave per token ----------------
__device__ __forceinline__ void router_body(const float* __restrict__ x,
                                            const float* __restrict__ wr,
                                            float* __restrict__ scores,
                                            int* __restrict__ cnt,
                                            int* __restrict__ list, int tk) {
  int lane = threadIdx.x & 63;
  const float* xr = x + (size_t)tk * H_;
  float acc[E_];
#pragma unroll
  for (int e = 0; e < E_; ++e) acc[e] = 0.f;
  int h0 = lane * 16;
#pragma unroll 4
  for (int i = 0; i < 16; ++i) {
    float xv = xr[h0 + i];
    const float* w = wr + (size_t)(h0 + i) * E_;
#pragma unroll
    for (int e = 0; e < E_; ++e) acc[e] = fmaf(xv, w[e], acc[e]);
  }
#pragma unroll
  for (int off = 32; off > 0; off >>= 1) {
#pragma unroll
    for (int e = 0; e < E_; ++e) acc[e] += __shfl_xor(acc[e], off, 64);
  }
  if (lane == 0) {
    int e0 = 0; float m0 = acc[0];
#pragma unroll
    for (int e = 1; e < E_; ++e) if (acc[e] > m0) { m0 = acc[e]; e0 = e; }
    int e1 = -1; float m1 = -1e30f;
#pragma unroll
    for (int e = 0; e < E_; ++e) if (e != e0 && acc[e] > m1) { m1 = acc[e]; e1 = e; }
    float s0 = 1.f / (1.f + __expf(m1 - m0));
    scores[tk * 2 + 0] = s0;
    scores[tk * 2 + 1] = 1.f - s0;
    int p0 = atomicAdd(&cnt[e0], 1); list[e0 * NTOK + p0] = tk * 2;
    int p1 = atomicAdd(&cnt[e1], 1); list[e1 * NTOK + p1] = tk * 2 + 1;
  }
}

// ================= FAST PATH =================

// prep: [0,512) router (4 tok/blk) | [512,1024) x->bf16 | [1024,8704) transpose
__global__ __launch_bounds__(256) void prep_k(
    const float* __restrict__ x, const float* __restrict__ wr,
    float* __restrict__ scores, int* __restrict__ cnt, int* __restrict__ list,
    u16* __restrict__ xb,
    const float* __restrict__ fc1, const float* __restrict__ fc2,
    const float* __restrict__ gw, const float* __restrict__ uw,
    const float* __restrict__ dw,
    u16* __restrict__ fc1T, u16* __restrict__ fc2T, u16* __restrict__ gwT,
    u16* __restrict__ uwT, u16* __restrict__ dwT) {
  __shared__ u16 lt[64][72];
  int bid = blockIdx.x, t = threadIdx.x;
  if (bid < 512) {
    router_body(x, wr, scores, cnt, list, bid * 4 + (t >> 6));
    return;
  }
  if (bid < 1024) {
    const float4* srcx = (const float4*)x;
    ushort4* dstx = (ushort4*)xb;
    int base = (bid - 512) * 1024 + t;
#pragma unroll
    for (int it = 0; it < 4; ++it) {
      float4 v = srcx[base + it * 256];
      ushort4 o;
      o.x = f2bf(v.x); o.y = f2bf(v.y); o.z = f2bf(v.z); o.w = f2bf(v.w);
      dstx[base + it * 256] = o;
    }
    return;
  }
  // 64x64 transpose-convert tiles: src [K][N] fp32 -> dst [N][K] bf16
  int r2 = bid - 1024;
  const float* src; u16* dst; int K, N, k0, n0;
  if (r2 < 4096) {
    int e = r2 >> 9, q = r2 & 511;
    src = fc1 + ((size_t)e << 21); dst = fc1T + ((size_t)e << 21);
    K = 1024; N = 2048; k0 = (q & 15) << 6; n0 = (q >> 4) << 6;
  } else if (r2 < 6144) {
    int rr = r2 - 4096; int e = rr >> 8, q = rr & 255;
    src = fc2 + ((size_t)e << 20); dst = fc2T + ((size_t)e << 20);
    K = 1024; N = 1024; k0 = (q & 15) << 6; n0 = (q >> 4) << 6;
  } else if (r2 < 6656) {
    int q = r2 - 6144; src = gw; dst = gwT;
    K = 1024; N = 2048; k0 = (q & 15) << 6; n0 = (q >> 4) << 6;
  } else if (r2 < 7168) {
    int q = r2 - 6656; src = uw; dst = uwT;
    K = 1024; N = 2048; k0 = (q & 15) << 6; n0 = (q >> 4) << 6;
  } else {
    int q = r2 - 7168; src = dw; dst = dwT;
    K = 2048; N = 1024; k0 = (q & 31) << 6; n0 = (q >> 5) << 6;
  }
#pragma unroll
  for (int it = 0; it < 4; ++it) {
    int lin = it * 256 + t; int rr = lin >> 4, c4 = lin & 15;
    float4 v = *(const float4*)(src + (size_t)(k0 + rr) * N + n0 + c4 * 4);
    lt[c4 * 4 + 0][rr] = f2bf(v.x);
    lt[c4 * 4 + 1][rr] = f2bf(v.y);
    lt[c4 * 4 + 2][rr] = f2bf(v.z);
    lt[c4 * 4 + 3][rr] = f2bf(v.w);
  }
  __syncthreads();
#pragma unroll
  for (int it = 0; it < 2; ++it) {
    int lin = it * 256 + t; int n = lin >> 3, kq = lin & 7;
    uint4 o = *(const uint4*)&lt[n][kq * 8];
    *(uint4*)(dst + (size_t)(n0 + n) * K + k0 + kq * 8) = o;
  }
}

// L1: fused SwiGLU GEMMs. bid<256: G3 dense (gw/uw). else G1 expert (fc1).
// 128x128 tile, BK=32, 4 waves (2x2), wave tile 64x64, 32 MFMA/K-step.
__global__ __launch_bounds__(256, 2) void swiglu_f_k(
    const u16* __restrict__ xb, const int* __restrict__ cnt,
    const int* __restrict__ list, const u16* __restrict__ fc1T,
    const u16* __restrict__ gwT, const u16* __restrict__ uwT,
    u16* __restrict__ act, u16* __restrict__ tmp) {
  __shared__ u16 As[128][32];
  __shared__ u16 B1s[128][32];
  __shared__ u16 B2s[128][32];
  int bid = blockIdx.x;
  int m0, n0, Me, obase = 0, ldo;
  const u16 *B1, *B2;
  const int* rowmap = nullptr;
  u16* Out;
  if (bid < 256) {  // G3: shared experts, all blocks active (scheduled first)
    int mb = bid >> 4, nb = bid & 15;
    m0 = mb * 128; n0 = nb * 128; Me = NTOK;
    B1 = gwT + (size_t)n0 * 1024; B2 = uwT + (size_t)n0 * 1024;
    Out = tmp; ldo = ISH_;
  } else {  // G1: expert fc1
    int b2 = bid - 256; int e = b2 >> 7, r = b2 & 127, mb = r >> 3, nb = r & 7;
    Me = cnt[e]; m0 = mb * 128;
    if (m0 >= Me) return;
    n0 = nb * 128;
    rowmap = list + e * NTOK;
    const u16* fe = fc1T + ((size_t)e << 21);
    B1 = fe + (size_t)n0 * 1024;
    B2 = fe + (size_t)(1024 + n0) * 1024;
    int off = 0;
    for (int q = 0; q < e; ++q) off += cnt[q];
    obase = off;
    Out = act; ldo = I_;
  }
  int t = threadIdx.x, wid = t >> 6, lane = t & 63;
  int wm = wid & 1, wn = wid >> 1, lr = lane & 15, lkg = lane >> 4;
  int cq = lane & 3, crw = lane >> 2;

  // per-thread global row pointers for this thread's 2 staging chunks
  const u16 *arow[2], *b1row[2], *b2row[2];
#pragma unroll
  for (int i = 0; i < 2; ++i) {
    int c = wid * 2 + i;
    int rl = m0 + c * 16 + crw;
    int rc = rl < Me ? rl : (Me - 1);
    int tok = rowmap ? (rowmap[rc] >> 1) : rc;
    arow[i] = xb + (size_t)tok * 1024 + cq * 8;
    int rb = c * 16 + crw;
    b1row[i] = B1 + (size_t)rb * 1024 + cq * 8;
    b2row[i] = B2 + (size_t)rb * 1024 + cq * 8;
  }
  u16* aL[2]; u16* b1L[2]; u16* b2L[2];
#pragma unroll
  for (int i = 0; i < 2; ++i) {
    int c = wid * 2 + i;
    aL[i] = (u16*)As + c * 512;
    b1L[i] = (u16*)B1s + c * 512;
    b2L[i] = (u16*)B2s + c * 512;
  }

  f32x4 aP[4][4] = {}, aG[4][4] = {};
  for (int k0 = 0; k0 < 1024; k0 += 32) {
#pragma unroll
    for (int i = 0; i < 2; ++i) {
      gl16(arow[i] + k0, aL[i]);
      gl16(b1row[i] + k0, b1L[i]);
      gl16(b2row[i] + k0, b2L[i]);
    }
    __syncthreads();
    bf16x8 af[4];
#pragma unroll
    for (int f = 0; f < 4; ++f)
      af[f] = *reinterpret_cast<const bf16x8*>(&As[wm * 64 + f * 16 + lr][lkg * 8]);
#pragma unroll
    for (int fn = 0; fn < 4; ++fn) {
      bf16x8 b1 = *reinterpret_cast<const bf16x8*>(&B1s[wn * 64 + fn * 16 + lr][lkg * 8]);
      bf16x8 b2 = *reinterpret_cast<const bf16x8*>(&B2s[wn * 64 + fn * 16 + lr][lkg * 8]);
#pragma unroll
      for (int fm = 0; fm < 4; ++fm) {
        aP[fm][fn] = __builtin_amdgcn_mfma_f32_16x16x32_bf16(af[fm], b1, aP[fm][fn], 0, 0, 0);
        aG[fm][fn] = __builtin_amdgcn_mfma_f32_16x16x32_bf16(af[fm], b2, aG[fm][fn], 0, 0, 0);
      }
    }
    __syncthreads();
  }
#pragma unroll
  for (int fm = 0; fm < 4; ++fm)
#pragma unroll
    for (int fn = 0; fn < 4; ++fn)
#pragma unroll
      for (int j = 0; j < 4; ++j) {
        int row = m0 + wm * 64 + fm * 16 + lkg * 4 + j;
        if (row < Me) {
          float p = aP[fm][fn][j], g = aG[fm][fn][j];
          float s = p / (1.f + __expf(-p)) * g;
          Out[(size_t)(obase + row) * ldo + n0 + wn * 64 + fn * 16 + lr] = f2bf(s);
        }
      }
}

// Plain GEMM. MODE 0: fc2 (K=1024, BN=128) -> outbuf[slot]*score (bf16).
//             MODE 1: down (K=2048, BN=64) -> out += outbuf[2t]+outbuf[2t+1].
template <int MODE>
__global__ __launch_bounds__(256, 2) void gemm_f_k(
    const u16* __restrict__ A, const u16* __restrict__ Bg,
    const int* __restrict__ cnt, const int* __restrict__ list,
    const float* __restrict__ scores, u16* __restrict__ outb,
    const u16* __restrict__ outb_r, float* __restrict__ out) {
  constexpr int BNx = MODE == 0 ? 128 : 64;
  constexpr int FN = BNx / 32;       // frags per wave in n
  constexpr int KK = MODE == 0 ? 1024 : 2048;
  constexpr int BCH = BNx / 64;      // B chunks per wave
  __shared__ u16 As[128][32];
  __shared__ u16 Bs[BNx][32];
  int bid = blockIdx.x;
  int e = 0, m0, n0, Me;
  const u16 *Ab, *Bb;
  if (MODE == 0) {
    e = bid >> 7; int r = bid & 127, mb = r >> 3, nb = r & 7;
    Me = cnt[e]; m0 = mb * 128;
    if (m0 >= Me) return;
    n0 = nb * 128;
    int off = 0;
    for (int q = 0; q < e; ++q) off += cnt[q];
    Ab = A + (size_t)off * KK;
    Bb = Bg + ((size_t)e << 20) + (size_t)n0 * KK;
  } else {
    int mb = bid >> 4, nb = bid & 15;
    m0 = mb * 128; n0 = nb * 64; Me = NTOK;
    Ab = A; Bb = Bg + (size_t)n0 * KK;
  }
  int t = threadIdx.x, wid = t >> 6, lane = t & 63;
  int wm = wid & 1, wn = wid >> 1, lr = lane & 15, lkg = lane >> 4;
  int cq = lane & 3, crw = lane >> 2;

  const u16* arow[2];
#pragma unroll
  for (int i = 0; i < 2; ++i) {
    int c = wid * 2 + i;
    int rl = m0 + c * 16 + crw;
    int rc = rl < Me ? rl : (Me - 1);
    arow[i] = Ab + (size_t)rc * KK + cq * 8;
  }
  const u16* brow[BCH];
#pragma unroll
  for (int i = 0; i < BCH; ++i) {
    int c = wid * BCH + i;
    brow[i] = Bb + (size_t)(c * 16 + crw) * KK + cq * 8;
  }

  f32x4 acc[4][FN] = {};
  for (int k0 = 0; k0 < KK; k0 += 32) {
#pragma unroll
    for (int i = 0; i < 2; ++i) gl16(arow[i] + k0, (u16*)As + (wid * 2 + i) * 512);
#pragma unroll
    for (int i = 0; i < BCH; ++i) gl16(brow[i] + k0, (u16*)Bs + (wid * BCH + i) * 512);
    __syncthreads();
    bf16x8 af[4];
#pragma unroll
    for (int f = 0; f < 4; ++f)
      af[f] = *reinterpret_cast<const bf16x8*>(&As[wm * 64 + f * 16 + lr][lkg * 8]);
#pragma unroll
    for (int fn = 0; fn < FN; ++fn) {
      bf16x8 bb = *reinterpret_cast<const bf16x8*>(&Bs[wn * (BNx / 2) + fn * 16 + lr][lkg * 8]);
#pragma unroll
      for (int fm = 0; fm < 4; ++fm)
        acc[fm][fn] = __builtin_amdgcn_mfma_f32_16x16x32_bf16(af[fm], bb, acc[fm][fn], 0, 0, 0);
    }
    __syncthreads();
  }
#pragma unroll
  for (int fm = 0; fm < 4; ++fm)
#pragma unroll
    for (int fn = 0; fn < FN; ++fn)
#pragma unroll
      for (int j = 0; j < 4; ++j) {
        int row = m0 + wm * 64 + fm * 16 + lkg * 4 + j;
        if (row < Me) {
          float v = acc[fm][fn][j];
          int c = n0 + wn * (BNx / 2) + fn * 16 + lr;
          if (MODE == 0) {
            int slot = list[e * NTOK + row];
            outb[(size_t)slot * H_ + c] = f2bf(v * scores[slot]);
          } else {
            out[(size_t)row * H_ + c] =
                v + bf2f(outb_r[(size_t)(2 * row) * H_ + c]) +
                bf2f(outb_r[(size_t)(2 * row + 1) * H_ + c]);
          }
        }
      }
}

// ================= FALLBACK PATH (R1, proven) =================
#define BM 128
#define BN 64
#define BK 32
#define PK (BK + 8)

__global__ void router_k(const float* __restrict__ x, const float* __restrict__ wr,
                         float* __restrict__ scores, int* __restrict__ cnt,
                         int* __restrict__ list) {
  int wid = threadIdx.x >> 6;
  int tk = blockIdx.x * 4 + wid;
  if (tk >= NTOK) return;
  router_body(x, wr, scores, cnt, list, tk);
}

__global__ void offs_k(const int* __restrict__ cnt, int* __restrict__ offs) {
  if (threadIdx.x == 0 && blockIdx.x == 0) {
    int s = 0;
    for (int e = 0; e < E_; ++e) { offs[e] = s; s += cnt[e]; }
  }
}

__global__ void cvt_k(const float* __restrict__ x, u16* __restrict__ xb, int n4) {
  int i = blockIdx.x * blockDim.x + threadIdx.x;
  if (i >= n4) return;
  float4 v = reinterpret_cast<const float4*>(x)[i];
  ushort4 o;
  o.x = f2bf(v.x); o.y = f2bf(v.y); o.z = f2bf(v.z); o.w = f2bf(v.w);
  reinterpret_cast<ushort4*>(xb)[i] = o;
}

template <int EXPERT>
__global__ __launch_bounds__(256) void swiglu_gemm_k(
    const u16* __restrict__ A, int lda,
    const int* __restrict__ list, const int* __restrict__ cnt, const int* __restrict__ offs,
    const float* __restrict__ B1g, const float* __restrict__ B2g, int ldb, long long bstride,
    u16* __restrict__ Out, int ldo, int K) {
  __shared__ u16 As[BM][PK];
  __shared__ u16 Bs[2][BN][PK];
  int e = EXPERT ? blockIdx.z : 0;
  int Me = EXPERT ? cnt[e] : NTOK;
  int m0 = blockIdx.y * BM;
  if (m0 >= Me) return;
  int n0 = blockIdx.x * BN;
  const int* rowmap = EXPERT ? (list + e * NTOK) : nullptr;
  const float* B1 = B1g + (EXPERT ? (long long)e * bstride : 0);
  const float* B2 = B2g + (EXPERT ? (long long)e * bstride : 0);
  int t = threadIdx.x, wid = t >> 6, lane = t & 63;
  int wm = wid & 1, wn = wid >> 1, lr = lane & 15, lkg = lane >> 4;
  f32x4 accP[4][2] = {}, accG[4][2] = {};
  for (int k0 = 0; k0 < K; k0 += BK) {
#pragma unroll
    for (int it = 0; it < 2; ++it) {
      int idx = it * 256 + t, r = idx >> 2, q = idx & 3, row = m0 + r;
      uint4 v = make_uint4(0u, 0u, 0u, 0u);
      if (row < Me) {
        int rg = EXPERT ? (rowmap[row] >> 1) : row;
        v = *reinterpret_cast<const uint4*>(A + (size_t)rg * lda + k0 + q * 8);
      }
      *reinterpret_cast<uint4*>(&As[r][q * 8]) = v;
    }
#pragma unroll
    for (int b = 0; b < 2; ++b) {
      const float* Bp = b ? B2 : B1;
#pragma unroll
      for (int it = 0; it < 2; ++it) {
        int idx = (it * 256 + t) * 4, kr = idx >> 6, c = idx & 63;
        float4 f = *reinterpret_cast<const float4*>(Bp + (size_t)(k0 + kr) * ldb + n0 + c);
        Bs[b][c + 0][kr] = f2bf(f.x); Bs[b][c + 1][kr] = f2bf(f.y);
        Bs[b][c + 2][kr] = f2bf(f.z); Bs[b][c + 3][kr] = f2bf(f.w);
      }
    }
    __syncthreads();
    bf16x8 af[4];
#pragma unroll
    for (int fm = 0; fm < 4; ++fm)
      af[fm] = *reinterpret_cast<const bf16x8*>(&As[wm * 64 + fm * 16 + lr][lkg * 8]);
#pragma unroll
    for (int fn = 0; fn < 2; ++fn) {
      bf16x8 bp = *reinterpret_cast<const bf16x8*>(&Bs[0][wn * 32 + fn * 16 + lr][lkg * 8]);
      bf16x8 bg = *reinterpret_cast<const bf16x8*>(&Bs[1][wn * 32 + fn * 16 + lr][lkg * 8]);
#pragma unroll
      for (int fm = 0; fm < 4; ++fm) {
        accP[fm][fn] = __builtin_amdgcn_mfma_f32_16x16x32_bf16(af[fm], bp, accP[fm][fn], 0, 0, 0);
        accG[fm][fn] = __builtin_amdgcn_mfma_f32_16x16x32_bf16(af[fm], bg, accG[fm][fn], 0, 0, 0);
      }
    }
    __syncthreads();
  }
#pragma unroll
  for (int fm = 0; fm < 4; ++fm)
#pragma unroll
    for (int fn = 0; fn < 2; ++fn)
#pragma unroll
      for (int j = 0; j < 4; ++j) {
        int grow = wm * 64 + fm * 16 + lkg * 4 + j, gcol = wn * 32 + fn * 16 + lr;
        int row = m0 + grow;
        if (row < Me) {
          float p = accP[fm][fn][j], g = accG[fm][fn][j];
          float s = p / (1.f + __expf(-p)) * g;
          int orow = EXPERT ? (offs[e] + row) : row;
          Out[(size_t)orow * ldo + n0 + gcol] = f2bf(s);
        }
      }
}

template <int EXPERT>
__global__ __launch_bounds__(256) void out_gemm_k(
    const u16* __restrict__ A, int lda,
    const int* __restrict__ cnt, const int* __restrict__ offs,
    const int* __restrict__ list, const float* __restrict__ scores,
    const float* __restrict__ Bg, int ldb, long long bstride,
    float* __restrict__ Out, const float* __restrict__ outbuf, int K) {
  __shared__ u16 As[BM][PK];
  __shared__ u16 Bs[BN][PK];
  int e = EXPERT ? blockIdx.z : 0;
  int Me = EXPERT ? cnt[e] : NTOK;
  int m0 = blockIdx.y * BM;
  if (m0 >= Me) return;
  int n0 = blockIdx.x * BN;
  const float* B = Bg + (EXPERT ? (long long)e * bstride : 0);
  int aoff = EXPERT ? offs[e] : 0;
  int t = threadIdx.x, wid = t >> 6, lane = t & 63;
  int wm = wid & 1, wn = wid >> 1, lr = lane & 15, lkg = lane >> 4;
  f32x4 acc[4][2] = {};
  for (int k0 = 0; k0 < K; k0 += BK) {
#pragma unroll
    for (int it = 0; it < 2; ++it) {
      int idx = it * 256 + t, r = idx >> 2, q = idx & 3, row = m0 + r;
      uint4 v = make_uint4(0u, 0u, 0u, 0u);
      if (row < Me)
        v = *reinterpret_cast<const uint4*>(A + (size_t)(aoff + row) * lda + k0 + q * 8);
      *reinterpret_cast<uint4*>(&As[r][q * 8]) = v;
    }
#pragma unroll
    for (int it = 0; it < 2; ++it) {
      int idx = (it * 256 + t) * 4, kr = idx >> 6, c = idx & 63;
      float4 f = *reinterpret_cast<const float4*>(B + (size_t)(k0 + kr) * ldb + n0 + c);
      Bs[c + 0][kr] = f2bf(f.x); Bs[c + 1][kr] = f2bf(f.y);
      Bs[c + 2][kr] = f2bf(f.z); Bs[c + 3][kr] = f2bf(f.w);
    }
    __syncthreads();
    bf16x8 af[4];
#pragma unroll
    for (int fm = 0; fm < 4; ++fm)
      af[fm] = *reinterpret_cast<const bf16x8*>(&As[wm * 64 + fm * 16 + lr][lkg * 8]);
#pragma unroll
    for (int fn = 0; fn < 2; ++fn) {
      bf16x8 bb = *reinterpret_cast<const bf16x8*>(&Bs[wn * 32 + fn * 16 + lr][lkg * 8]);
#pragma unroll
      for (int fm = 0; fm < 4; ++fm)
        acc[fm][fn] = __builtin_amdgcn_mfma_f32_16x16x32_bf16(af[fm], bb, acc[fm][fn], 0, 0, 0);
    }
    __syncthreads();
  }
#pragma unroll
  for (int fm = 0; fm < 4; ++fm)
#pragma unroll
    for (int fn = 0; fn < 2; ++fn)
#pragma unroll
      for (int j = 0; j < 4; ++j) {
        int grow = wm * 64 + fm * 16 + lkg * 4 + j, gcol = wn * 32 + fn * 16 + lr;
        int row = m0 + grow;
        if (row < Me) {
          float v = acc[fm][fn][j];
          int c = n0 + gcol;
          if (EXPERT) {
            int slot = list[e * NTOK + row];
            Out[(size_t)slot * H_ + c] = v * scores[slot];
          } else {
            Out[(size_t)row * H_ + c] =
                v + outbuf[(size_t)(2 * row) * H_ + c] + outbuf[(size_t)(2 * row + 1) * H_ + c];
          }
        }
      }
}

// ---------------------------------------------------------------------------
extern "C" void kernel_launch(void* const* d_in, const int* in_sizes, int n_in,
                              void* d_out, int out_size, void* d_ws, size_t ws_size,
                              hipStream_t stream) {
  const float* x   = (const float*)d_in[0];
  const float* wr  = (const float*)d_in[1];
  const float* fc1 = (const float*)d_in[2];
  const float* fc2 = (const float*)d_in[3];
  const float* gw  = (const float*)d_in[4];
  const float* uw  = (const float*)d_in[5];
  const float* dw  = (const float*)d_in[6];
  float* out = (float*)d_out;
  char* ws = (char*)d_ws;

  const size_t NEED_FAST = 131072ull + (88ull << 20);
  if (ws_size >= NEED_FAST) {
    float* scores = (float*)ws;
    int* cnt  = (int*)(ws + 16384);
    int* list = (int*)(ws + 16512);
    u16* xb   = (u16*)(ws + 131072);
    u16* act  = (u16*)(ws + 131072 + (4ll << 20));
    u16* tmp  = (u16*)(ws + 131072 + (12ll << 20));
    u16* outb = (u16*)(ws + 131072 + (20ll << 20));
    u16* fc1T = (u16*)(ws + 131072 + (28ll << 20));
    u16* fc2T = (u16*)(ws + 131072 + (60ll << 20));
    u16* gwT  = (u16*)(ws + 131072 + (76ll << 20));
    u16* uwT  = (u16*)(ws + 131072 + (80ll << 20));
    u16* dwT  = (u16*)(ws + 131072 + (84ll << 20));

    hipMemsetAsync(cnt, 0, 128, stream);
    prep_k<<<8704, 256, 0, stream>>>(x, wr, scores, cnt, list, xb,
                                     fc1, fc2, gw, uw, dw, fc1T, fc2T, gwT, uwT, dwT);
    swiglu_f_k<<<1280, 256, 0, stream>>>(xb, cnt, list, fc1T, gwT, uwT, act, tmp);
    gemm_f_k<0><<<1024, 256, 0, stream>>>(act, fc2T, cnt, list, scores, outb, nullptr, nullptr);
    gemm_f_k<1><<<256, 256, 0, stream>>>(tmp, dwT, nullptr, nullptr, nullptr, nullptr, outb, out);
  } else {
    float* scores = (float*)(ws);
    int*   cnt    = (int*)(ws + (16 << 10));
    int*   offs   = (int*)(ws + (16 << 10) + 128);
    int*   list   = (int*)(ws + (16 << 10) + 256);
    u16*   xb     = (u16*)(ws + (96 << 10));
    u16*   act    = (u16*)(ws + (96 << 10) + (4ll << 20));
    u16*   tmp    = (u16*)(ws + (96 << 10) + (12ll << 20));
    float* outbuf = (float*)(ws + (96 << 10) + (20ll << 20));

    hipMemsetAsync(cnt, 0, E_ * sizeof(int), stream);
    router_k<<<NTOK / 4, 256, 0, stream>>>(x, wr, scores, cnt, list);
    offs_k<<<1, 64, 0, stream>>>(cnt, offs);
    cvt_k<<<(NTOK * H_ / 4 + 255) / 256, 256, 0, stream>>>(x, xb, NTOK * H_ / 4);
    swiglu_gemm_k<1><<<dim3(I_ / BN, NTOK / BM, E_), 256, 0, stream>>>(
        xb, H_, list, cnt, offs, fc1, fc1 + I_, 2 * I_, (long long)H_ * 2 * I_, act, I_, H_);
    out_gemm_k<1><<<dim3(H_ / BN, NTOK / BM, E_), 256, 0, stream>>>(
        act, I_, cnt, offs, list, scores, fc2, H_, (long long)I_ * H_, outbuf, nullptr, I_);
    swiglu_gemm_k<0><<<dim3(ISH_ / BN, NTOK / BM, 1), 256, 0, stream>>>(
        xb, H_, nullptr, nullptr, nullptr, gw, uw, ISH_, 0, tmp, ISH_, H_);
    out_gemm_k<0><<<dim3(H_ / BN, NTOK / BM, 1), 256, 0, stream>>>(
        tmp, ISH_, nullptr, nullptr, nullptr, nullptr, dw, H_, 0, out, outbuf, ISH_);
  }
  (void)in_sizes; (void)n_in; (void)out_size;
}